// Round 7
// baseline (655.556 us; speedup 1.0000x reference)
//
#include <hip/hip_runtime.h>
#include <hip/hip_bf16.h>
#include <hip/hip_fp16.h>

// GCN: 2x GCNConv (symmetric norm, self-loops) + linear head.
// N=100000, E=3200000, IN=128, HID=64, LAB=121.
//
// R7: aggregate fused with the downstream GEMM (agg_mm): 64 rows/block,
// phase 1 = CSR gather + relu into LDS h-rows (unroll 16), phase 2 =
// register-tile GEMM (h@W) from LDS, writing the next layer's input
// directly. Removes hbuf (2x 25.6 MB write + read), GEMM2 + head launches.
// hs LDS stride 68 = conflict-free b128 row reads.
// Retained: two-level dst sort (block-private full-line runs), fp16 feat
// buffers (128B gather rows, 12.8 MB working set), bucket_sort emits
// row_ptr+dinv, self-loop folded as deg+1 + epilogue term, dinv[src]
// folded into GEMM rowscale.

#define IN_DIM 128
#define HID 64
#define N_LAB 121
#define NB_BLK 256        // level-1 blocks (chunks)

// ---- generic 3-kernel exclusive scan (used for the M1 = nbuk*NB_BLK counts) ----
__global__ void scan1(const int* __restrict__ in, int* __restrict__ out,
                      int* __restrict__ bsums, int n) {
    __shared__ int s[256];
    int i = blockIdx.x * 256 + threadIdx.x;
    int v = (i < n) ? in[i] : 0;
    s[threadIdx.x] = v;
    __syncthreads();
    for (int off = 1; off < 256; off <<= 1) {
        int t = (threadIdx.x >= off) ? s[threadIdx.x - off] : 0;
        __syncthreads();
        s[threadIdx.x] += t;
        __syncthreads();
    }
    if (i < n) out[i] = s[threadIdx.x] - v;  // exclusive
    if (threadIdx.x == 255) bsums[blockIdx.x] = s[255];
}

__global__ void scan2(int* __restrict__ bsums, int nb) {  // single block, nb <= 512
    __shared__ int s[512];
    int v = (threadIdx.x < nb) ? bsums[threadIdx.x] : 0;
    s[threadIdx.x] = v;
    __syncthreads();
    for (int off = 1; off < 512; off <<= 1) {
        int t = (threadIdx.x >= off) ? s[threadIdx.x - off] : 0;
        __syncthreads();
        s[threadIdx.x] += t;
        __syncthreads();
    }
    if (threadIdx.x < nb) bsums[threadIdx.x] = s[threadIdx.x] - v;  // exclusive
}

__global__ void scan_add(int* __restrict__ out, const int* __restrict__ bsums, int n) {
    int i = blockIdx.x * 256 + threadIdx.x;
    if (i < n) out[i] += bsums[blockIdx.x];
}

// ---- L1 pass A: per-block per-bucket counts ----
__global__ __launch_bounds__(256) void bucket_count(const int* __restrict__ dst,
                                                    int* __restrict__ counts,
                                                    int nbuk, int chunk, int E) {
    extern __shared__ int c[];
    for (int j = threadIdx.x; j < nbuk; j += 256) c[j] = 0;
    __syncthreads();
    int beg = blockIdx.x * chunk;
    int end = min(beg + chunk, E);
    for (int i = beg + threadIdx.x; i < end; i += 256)
        atomicAdd(&c[dst[i] >> 8], 1);
    __syncthreads();
    for (int j = threadIdx.x; j < nbuk; j += 256)
        counts[j * NB_BLK + blockIdx.x] = c[j];
}

// ---- L1 pass B: scatter into private contiguous runs ----
__global__ __launch_bounds__(256) void bucket_scatter(const int* __restrict__ src,
                                                      const int* __restrict__ dst,
                                                      const int* __restrict__ base,
                                                      int* __restrict__ bucketed,
                                                      int nbuk, int chunk, int E) {
    extern __shared__ int c[];
    for (int j = threadIdx.x; j < nbuk; j += 256) c[j] = 0;
    __syncthreads();
    int beg = blockIdx.x * chunk;
    int end = min(beg + chunk, E);
    for (int i = beg + threadIdx.x; i < end; i += 256) {
        int d = dst[i];
        int b = d >> 8;
        int r = atomicAdd(&c[b], 1);
        int pos = base[b * NB_BLK + blockIdx.x] + r;
        bucketed[pos] = ((d & 255) << 17) | src[i];  // src < 2^17
    }
}

// ---- L2: within-bucket sort into final CSR srcs; emits row_ptr + dinv ----
__global__ __launch_bounds__(256) void bucket_sort(const int* __restrict__ bucketed,
                                                   const int* __restrict__ base,
                                                   int* __restrict__ srcs,
                                                   int* __restrict__ row_ptr,
                                                   float* __restrict__ dinv,
                                                   int nbuk, int N, int E) {
    __shared__ int h[256];
    __shared__ int cur[256];
    int b = blockIdx.x;
    int nodeBase = b << 8;
    int s = base[b * NB_BLK];
    int e = (b == nbuk - 1) ? E : base[(b + 1) * NB_BLK];
    h[threadIdx.x] = 0;
    __syncthreads();
    for (int i = s + threadIdx.x; i < e; i += 256)
        atomicAdd(&h[bucketed[i] >> 17], 1);
    __syncthreads();
    int v = h[threadIdx.x];
    for (int off = 1; off < 256; off <<= 1) {  // inclusive Hillis-Steele
        int t = (threadIdx.x >= off) ? h[threadIdx.x - off] : 0;
        __syncthreads();
        h[threadIdx.x] += t;
        __syncthreads();
    }
    int excl = h[threadIdx.x] - v;
    cur[threadIdx.x] = excl;
    int node = nodeBase + threadIdx.x;
    if (node < N) {
        row_ptr[node] = s + excl;
        dinv[node] = rsqrtf((float)v + 1.0f);  // +1 = self loop
    }
    if (b == nbuk - 1 && threadIdx.x == 0) row_ptr[N] = E;
    __syncthreads();
    for (int i = s + threadIdx.x; i < e; i += 256) {
        int p = bucketed[i];
        int d = p >> 17;
        int r = atomicAdd(&cur[d], 1);
        srcs[s + r] = p & 0x1FFFF;
    }
}

// ---- C[M,N] = (A[M,K] @ B[K,N]) * rowscale[r] + bias. LDS-staged, 2D reg tile ----
template <int K, int N, typename OT>
__global__ __launch_bounds__(256) void gemm_kernel(
        const float* __restrict__ A, const float* __restrict__ B,
        const float* __restrict__ bias, const float* __restrict__ rowscale,
        OT* __restrict__ C, int M) {
    constexpr int ROWS = 64;
    constexpr int NPAD = (N <= 64) ? 64 : 128;
    constexpr int CG = NPAD / 4;     // column groups
    constexpr int RG = 256 / CG;     // thread rows
    constexpr int RPT = ROWS / RG;   // rows per thread
    __shared__ float Bs[K * NPAD];
    __shared__ float As[ROWS * K];

    for (int i = threadIdx.x; i < K * NPAD; i += 256) {
        int c = i & (NPAD - 1);
        int k = i / NPAD;
        Bs[i] = (c < N) ? B[k * N + c] : 0.f;
    }
    const int row_base = blockIdx.x * ROWS;
    const float* Ablk = A + (size_t)row_base * K;
    int avail = (M - row_base) * K;
    if (avail > ROWS * K) avail = ROWS * K;
    const int nvec = avail >> 2;  // K % 4 == 0
    const float4* __restrict__ Av = (const float4*)Ablk;
    float4* Asv = (float4*)As;
    for (int i = threadIdx.x; i < nvec; i += 256) Asv[i] = Av[i];
    __syncthreads();

    const int cg = threadIdx.x % CG;
    const int rg = threadIdx.x / CG;

    float acc[RPT][4];
    #pragma unroll
    for (int j = 0; j < RPT; ++j) {
        acc[j][0] = 0.f; acc[j][1] = 0.f; acc[j][2] = 0.f; acc[j][3] = 0.f;
    }

    for (int k = 0; k < K; k += 4) {
        float4 Bq[4];
        #pragma unroll
        for (int kk = 0; kk < 4; ++kk)
            Bq[kk] = *(const float4*)&Bs[(k + kk) * NPAD + cg * 4];
        #pragma unroll
        for (int j = 0; j < RPT; ++j) {
            const float4 Aq = *(const float4*)&As[(rg + RG * j) * K + k];
            #pragma unroll
            for (int c = 0; c < 4; ++c) {
                float a = acc[j][c];
                a = fmaf(Aq.x, ((const float*)&Bq[0])[c], a);
                a = fmaf(Aq.y, ((const float*)&Bq[1])[c], a);
                a = fmaf(Aq.z, ((const float*)&Bq[2])[c], a);
                a = fmaf(Aq.w, ((const float*)&Bq[3])[c], a);
                acc[j][c] = a;
            }
        }
    }

    float bv[4];
    #pragma unroll
    for (int c = 0; c < 4; ++c) {
        int col = cg * 4 + c;
        bv[c] = (bias && col < N) ? bias[col] : 0.f;
    }

    #pragma unroll
    for (int j = 0; j < RPT; ++j) {
        const int r = row_base + rg + RG * j;
        if (r >= M) continue;
        const float sc = rowscale ? rowscale[r] : 1.0f;
        float o[4];
        #pragma unroll
        for (int c = 0; c < 4; ++c) o[c] = fmaf(acc[j][c], sc, bv[c]);
        OT* Crow = C + (size_t)r * N;
        if constexpr (sizeof(OT) == 4 && (N % 4 == 0)) {
            *(float4*)&Crow[cg * 4] = make_float4(o[0], o[1], o[2], o[3]);
        } else if constexpr (sizeof(OT) == 2 && (N % 4 == 0)) {
            __half2* p = (__half2*)&Crow[cg * 4];
            p[0] = __floats2half2_rn(o[0], o[1]);
            p[1] = __floats2half2_rn(o[2], o[3]);
        } else {
            #pragma unroll
            for (int c = 0; c < 4; ++c) {
                int col = cg * 4 + c;
                if (col < N) Crow[col] = (OT)o[c];
            }
        }
    }
}

// ---- fused aggregate + GEMM: 64 rows per block ----
// Phase 1 (per wave, lanes = 64 feats): for each of its 16 rows,
//   h[r][f] = relu(dinv[r]*(feat_in[r][f] + sum_{s in N(r)} feat_in[s][f]) + bias_agg[f])
//   -> LDS hs (stride 68: conflict-free b128 row reads in phase 2).
// Phase 2: register-tile GEMM out[r] = (h[r] @ W) * (ROWSCALE?dinv[r]:1) + bias_out.
// Fusion A (layer1->2): NOUT=64, ROWSCALE=1, bias_out=null, OT=half -> feat2b.
// Fusion B (layer2->head): NOUT=121, ROWSCALE=0, bias_out=bout, OT=float -> logits.
template <int NOUT, bool ROWSCALE, typename OT>
__global__ __launch_bounds__(256) void agg_mm(
        const __half* __restrict__ feat_in, const int* __restrict__ rp,
        const int* __restrict__ srcs, const float* __restrict__ dinv,
        const float* __restrict__ bias_agg, const float* __restrict__ W,
        const float* __restrict__ bias_out, OT* __restrict__ out, int N) {
    constexpr int NPAD = (NOUT <= 64) ? 64 : 128;
    constexpr int CG = NPAD / 4;
    constexpr int RG = 256 / CG;
    constexpr int RPT = 64 / RG;
    constexpr int HSTR = 68;         // padded h-row stride (floats)
    __shared__ float hs[64 * HSTR];
    __shared__ float Ws[64 * NPAD];
    __shared__ float dv[64];

    // stage W (zero-pad cols NOUT..NPAD) — completes by the syncthreads below
    for (int i = threadIdx.x; i < 64 * NPAD; i += 256) {
        int c = i & (NPAD - 1);
        int k = i / NPAD;
        Ws[i] = (c < NOUT) ? W[k * NOUT + c] : 0.f;
    }

    const int row_base = blockIdx.x * 64;
    const int f = threadIdx.x & 63;
    const int ry = threadIdx.x >> 6;
    const float bagg = bias_agg[f];

    // ---- phase 1: gather + relu -> hs ----
    for (int t = 0; t < 16; ++t) {
        const int j = ry + 4 * t;
        const int r = row_base + j;
        float val = 0.f;
        if (r < N) {
            const float di = dinv[r];
            if (f == 0) dv[j] = di;
            int beg = rp[r], end = rp[r + 1];
            float acc = __half2float(feat_in[((size_t)r << 6) + f]);  // self loop
            int e = beg;
            for (; e + 16 <= end; e += 16) {   // 16 gathers in flight
                int si[16];
                #pragma unroll
                for (int i = 0; i < 16; ++i) si[i] = srcs[e + i];
                float v[16];
                #pragma unroll
                for (int i = 0; i < 16; ++i)
                    v[i] = __half2float(feat_in[((size_t)si[i] << 6) + f]);
                #pragma unroll
                for (int i = 0; i < 16; ++i) acc += v[i];
            }
            for (; e + 4 <= end; e += 4) {
                int s0 = srcs[e], s1 = srcs[e + 1], s2 = srcs[e + 2], s3 = srcs[e + 3];
                float v0 = __half2float(feat_in[((size_t)s0 << 6) + f]);
                float v1 = __half2float(feat_in[((size_t)s1 << 6) + f]);
                float v2 = __half2float(feat_in[((size_t)s2 << 6) + f]);
                float v3 = __half2float(feat_in[((size_t)s3 << 6) + f]);
                acc += v0; acc += v1; acc += v2; acc += v3;
            }
            for (; e < end; ++e) acc += __half2float(feat_in[((size_t)srcs[e] << 6) + f]);
            val = fmaxf(fmaf(acc, di, bagg), 0.f);
        } else if (f == 0) {
            dv[j] = 0.f;
        }
        hs[j * HSTR + f] = val;
    }
    __syncthreads();

    // ---- phase 2: out[r] = (h[r] @ Ws) * sc + bias_out ----
    const int cg = threadIdx.x % CG;
    const int rg = threadIdx.x / CG;

    float acc[RPT][4];
    #pragma unroll
    for (int j = 0; j < RPT; ++j) {
        acc[j][0] = 0.f; acc[j][1] = 0.f; acc[j][2] = 0.f; acc[j][3] = 0.f;
    }
    for (int k = 0; k < 64; k += 4) {
        float4 Bq[4];
        #pragma unroll
        for (int kk = 0; kk < 4; ++kk)
            Bq[kk] = *(const float4*)&Ws[(k + kk) * NPAD + cg * 4];
        #pragma unroll
        for (int j = 0; j < RPT; ++j) {
            const float4 Aq = *(const float4*)&hs[(rg + RG * j) * HSTR + k];
            #pragma unroll
            for (int c = 0; c < 4; ++c) {
                float a = acc[j][c];
                a = fmaf(Aq.x, ((const float*)&Bq[0])[c], a);
                a = fmaf(Aq.y, ((const float*)&Bq[1])[c], a);
                a = fmaf(Aq.z, ((const float*)&Bq[2])[c], a);
                a = fmaf(Aq.w, ((const float*)&Bq[3])[c], a);
                acc[j][c] = a;
            }
        }
    }

    float bv[4];
    #pragma unroll
    for (int c = 0; c < 4; ++c) {
        int col = cg * 4 + c;
        bv[c] = (bias_out && col < NOUT) ? bias_out[col] : 0.f;
    }

    #pragma unroll
    for (int j = 0; j < RPT; ++j) {
        const int lr = rg + RG * j;
        const int r = row_base + lr;
        if (r >= N) continue;
        const float sc = ROWSCALE ? dv[lr] : 1.0f;
        float o[4];
        #pragma unroll
        for (int c = 0; c < 4; ++c) o[c] = fmaf(acc[j][c], sc, bv[c]);
        OT* Crow = out + (size_t)r * NOUT;
        if constexpr (sizeof(OT) == 2 && (NOUT % 4 == 0)) {
            __half2* p = (__half2*)&Crow[cg * 4];
            p[0] = __floats2half2_rn(o[0], o[1]);
            p[1] = __floats2half2_rn(o[2], o[3]);
        } else if constexpr (sizeof(OT) == 4 && (NOUT % 4 == 0)) {
            *(float4*)&Crow[cg * 4] = make_float4(o[0], o[1], o[2], o[3]);
        } else {
            #pragma unroll
            for (int c = 0; c < 4; ++c) {
                int col = cg * 4 + c;
                if (col < NOUT) Crow[col] = (OT)o[c];
            }
        }
    }
}

extern "C" void kernel_launch(void* const* d_in, const int* in_sizes, int n_in,
                              void* d_out, int out_size, void* d_ws, size_t ws_size,
                              hipStream_t stream) {
    const float* x    = (const float*)d_in[0];
    const int*   ei   = (const int*)d_in[1];
    const float* W1   = (const float*)d_in[2];
    const float* b1   = (const float*)d_in[3];
    const float* W2   = (const float*)d_in[4];
    const float* b2   = (const float*)d_in[5];
    const float* Wout = (const float*)d_in[6];
    const float* bout = (const float*)d_in[7];
    float* out = (float*)d_out;

    const int N = in_sizes[0] / IN_DIM;   // 100000
    const int E = in_sizes[1] / 2;        // 3200000
    const int* srcI = ei;
    const int* dstI = ei + E;

    const int nbuk = (N + 255) >> 8;      // 391 coarse buckets
    const int M1 = nbuk * NB_BLK;         // 100096 count entries
    const int chunk = (E + NB_BLK - 1) / NB_BLK;

    // workspace carve-up
    int*    row_ptr = (int*)d_ws;                   // [N+1]
    float*  dinv    = (float*)(row_ptr + (N + 1));  // [N]
    int*    counts  = (int*)(dinv + N);             // [M1]
    int*    base    = counts + M1;                  // [M1]
    int*    bsums2  = base + M1;                    // [512]
    int*    srcs    = bsums2 + 512;                 // [E]
    __half* feat2a  = (__half*)(srcs + E);          // [N, HID] fp16 (12.8 MB)
    __half* feat2b  = feat2a + (size_t)N * HID;     // [N, HID] fp16
    int*    bucketed = (int*)feat2a;                // [E] ints, aliases feat2a (dead until GEMM1)

    const int nbM = (M1 + 255) / 256;               // 391
    const int gemmBlocks = (N + 63) / 64;           // 1563
    const size_t ldsBuk = (size_t)nbuk * sizeof(int);

    // ---- two-level sort: edges grouped by dst into srcs; emits row_ptr+dinv ----
    bucket_count<<<NB_BLK, 256, ldsBuk, stream>>>(dstI, counts, nbuk, chunk, E);
    scan1<<<nbM, 256, 0, stream>>>(counts, base, bsums2, M1);
    scan2<<<1, 512, 0, stream>>>(bsums2, nbM);
    scan_add<<<nbM, 256, 0, stream>>>(base, bsums2, M1);
    bucket_scatter<<<NB_BLK, 256, ldsBuk, stream>>>(srcI, dstI, base, bucketed, nbuk, chunk, E);
    bucket_sort<<<nbuk, 256, 0, stream>>>(bucketed, base, srcs, row_ptr, dinv, nbuk, N, E);

    // ---- layer 1 GEMM: feat2a = (x@W1)*dinv ----
    gemm_kernel<IN_DIM, HID, __half><<<gemmBlocks, 256, 0, stream>>>(x, W1, nullptr, dinv, feat2a, N);

    // ---- fused: h1 = relu(agg(feat2a)*dinv + b1); feat2b = (h1@W2)*dinv ----
    agg_mm<HID, true, __half><<<gemmBlocks, 256, 0, stream>>>(
        feat2a, row_ptr, srcs, dinv, b1, W2, nullptr, feat2b, N);

    // ---- fused: h2 = relu(agg(feat2b)*dinv + b2); out = h2@Wout + bout ----
    agg_mm<N_LAB, false, float><<<gemmBlocks, 256, 0, stream>>>(
        feat2b, row_ptr, srcs, dinv, b2, Wout, bout, out, N);
}